// Round 1
// 968.090 us; speedup vs baseline: 1.0094x; 1.0094x over previous
//
#include <hip/hip_runtime.h>

#define T_ 6
#define B_ 8
#define C_ 192
#define H_ 112
#define W_ 112
#define K_ 3
#define H0_ 56
#define W0_ 56
#define N_ (T_ * K_)      // 18
#define HW_ (H_ * W_)     // 12544
#define HW0_ (H0_ * W0_)  // 3136
#define CODE_BLOCKS 588   // B*T*HW0 / 256 = 150528/256 exactly

// ---------------------------------------------------------------------------
// Kernel A (fused prep):
//  blocks [0,588):   pack 3 binary masks into a 3-bit code per (b,t,h0,w0)
//  blocks [588,780): Wf[c][e] = sum_d W_emb[d][c] * W_gcn[d][e]
//                    (algebraic fusion: support = node @ (W_emb^T @ W_gcn),
//                     eliminates the stride-768B W_emb gather entirely)
// ---------------------------------------------------------------------------
__global__ __launch_bounds__(256) void prep_kernel(
    const int* __restrict__ masks, unsigned char* __restrict__ code,
    const float* __restrict__ W_emb, const float* __restrict__ W_gcn,
    float* __restrict__ Wf) {
  int blk = blockIdx.x;
  if (blk < CODE_BLOCKS) {
    int idx = blk * 256 + threadIdx.x;  // over B*T*H0*W0 = 150528 (exact)
    int p = idx % HW0_;
    int bt = idx / HW0_;  // b*T + t
    const int base = bt * K_ * HW0_;
    int c0 = masks[base + 0 * HW0_ + p];
    int c1 = masks[base + 1 * HW0_ + p];
    int c2 = masks[base + 2 * HW0_ + p];
    code[idx] = (unsigned char)((c0 & 1) | ((c1 & 1) << 1) | ((c2 & 1) << 2));
  } else {
    int c = blk - CODE_BLOCKS;  // 0..191
    int e = threadIdx.x;
    if (e < C_) {
      float s = 0.f;
      // W_emb[d*C+c] is wave-uniform (scalar path); W_gcn[d*C+e] coalesced.
#pragma unroll 4
      for (int d = 0; d < C_; ++d) s += W_emb[d * C_ + c] * W_gcn[d * C_ + e];
      Wf[c * C_ + e] = s;
    }
  }
}

// ---------------------------------------------------------------------------
// Kernel B: masked pooling. One block per (t,b,c) plane (x layout order).
// feat[b][t][k][c] = (1/HW) * sum_{h,w} x[t,b,c,h,w] * m[b,t,k,h,w]
// (scaling folded in here so gcn consumes node directly)
// ---------------------------------------------------------------------------
__global__ __launch_bounds__(256) void pool_kernel(
    const float* __restrict__ x, const unsigned char* __restrict__ code,
    float* __restrict__ feat) {
  int blk = blockIdx.x;  // (t*B + b)*C + c
  int c = blk % C_;
  int tb = blk / C_;  // t*B + b
  int b = tb % B_;
  int t = tb / B_;

  const float4* xp = (const float4*)(x + (size_t)blk * HW_);
  const unsigned char* cp = code + (b * T_ + t) * HW0_;

  float s0 = 0.f, s1 = 0.f, s2 = 0.f;
  // W_=112 divisible by 4 -> each float4 stays within one row.
  for (int i = threadIdx.x; i < HW_ / 4; i += 256) {
    float4 v = xp[i];
    int p = i * 4;
    int h = p / W_;
    int w = p - h * W_;
    const unsigned char* crow = cp + (h >> 1) * W0_ + (w >> 1);
    int ca = crow[0];  // covers pixels w, w+1
    int cb = crow[1];  // covers pixels w+2, w+3
    float pa = v.x + v.y;
    float pb = v.z + v.w;
    s0 += (ca & 1 ? pa : 0.f) + (cb & 1 ? pb : 0.f);
    s1 += (ca & 2 ? pa : 0.f) + (cb & 2 ? pb : 0.f);
    s2 += (ca & 4 ? pa : 0.f) + (cb & 4 ? pb : 0.f);
  }

  // wave (64-lane) reduce, then LDS across the 4 waves
  for (int off = 32; off > 0; off >>= 1) {
    s0 += __shfl_down(s0, off);
    s1 += __shfl_down(s1, off);
    s2 += __shfl_down(s2, off);
  }
  __shared__ float red[4][3];
  int lane = threadIdx.x & 63;
  int wid = threadIdx.x >> 6;
  if (lane == 0) {
    red[wid][0] = s0;
    red[wid][1] = s1;
    red[wid][2] = s2;
  }
  __syncthreads();
  if (threadIdx.x == 0) {
    const float inv_hw = 1.0f / (float)HW_;
    float f0 = (red[0][0] + red[1][0] + red[2][0] + red[3][0]) * inv_hw;
    float f1 = (red[0][1] + red[1][1] + red[2][1] + red[3][1]) * inv_hw;
    float f2 = (red[0][2] + red[1][2] + red[2][2] + red[3][2]) * inv_hw;
    float* fb = feat + ((b * T_ + t) * K_) * C_ + c;
    fb[0 * C_] = f0;
    fb[1 * C_] = f1;
    fb[2 * C_] = f2;
  }
}

// ---------------------------------------------------------------------------
// Kernel C: per-batch GCN, restructured.
//   node = feat (already /HW); adj = softmax(node node^T);
//   sup  = node @ Wf          (coalesced: lane index = e)
//   outk = adj @ sup + b_gcn
// One block per b (grid = 8) — total work is now ~0.7 MFLOP/block, all
// coalesced or LDS-resident, so 8 blocks finish in a few µs.
// ---------------------------------------------------------------------------
__global__ __launch_bounds__(256) void gcn_kernel(
    const float* __restrict__ feat, const float* __restrict__ Wf,
    const float* __restrict__ b_gcn, float* __restrict__ outk) {
  int b = blockIdx.x;
  int tid = threadIdx.x;
  __shared__ float node[N_][C_ + 1];  // +1: odd stride breaks gram's 18-way
                                      // same-bank conflict (192%32==0)
  __shared__ float sup[N_][C_];
  __shared__ float adj[N_][N_];

  for (int i = tid; i < N_ * C_; i += 256)
    node[i / C_][i % C_] = feat[b * N_ * C_ + i];
  __syncthreads();

  // gram
  for (int i = tid; i < N_ * N_; i += 256) {
    int n = i / N_, m = i % N_;
    float s = 0.f;
#pragma unroll 8
    for (int c = 0; c < C_; ++c) s += node[n][c] * node[m][c];
    adj[n][m] = s;
  }
  __syncthreads();

  // softmax rows (18 rows, one thread each; fully unrolled -> registers)
  if (tid < N_) {
    float mx = -1e30f;
#pragma unroll
    for (int m = 0; m < N_; ++m) mx = fmaxf(mx, adj[tid][m]);
    float tmp[N_];
    float sum = 0.f;
#pragma unroll
    for (int m = 0; m < N_; ++m) {
      tmp[m] = __expf(adj[tid][m] - mx);
      sum += tmp[m];
    }
    float inv = 1.0f / sum;
#pragma unroll
    for (int m = 0; m < N_; ++m) adj[tid][m] = tmp[m] * inv;
  }
  __syncthreads();

  // sup[n][e] = sum_c node[n][c] * Wf[c][e]
  // node[n][c] wave-uniform broadcast; Wf read coalesced (lane = e), L2-hot.
  for (int i = tid; i < N_ * C_; i += 256) {
    int n = i / C_, e = i % C_;
    float s = 0.f;
#pragma unroll 4
    for (int c = 0; c < C_; ++c) s += node[n][c] * Wf[c * C_ + e];
    sup[n][e] = s;
  }
  __syncthreads();

  // outk[n][e] = sum_m adj[n][m] * sup[m][e] + b_gcn[e]
  for (int i = tid; i < N_ * C_; i += 256) {
    int n = i / C_, e = i % C_;
    float s = b_gcn[e];
#pragma unroll
    for (int m = 0; m < N_; ++m) s += adj[n][m] * sup[m][e];
    outk[b * N_ * C_ + i] = s;
  }
}

// ---------------------------------------------------------------------------
// Kernel D: out = x + sum_k outk[b,t,k,c] * m[b,t,k,h,w]. One block per
// (t,b,c) plane, iterated in REVERSE plane order: pool just streamed x
// ascending, so the Infinity Cache (256 MB) holds the tail of x — reading
// high planes first converts up to ~200 MB of this kernel's fetch into L3
// hits.
// ---------------------------------------------------------------------------
__global__ __launch_bounds__(256) void out_kernel(
    const float* __restrict__ x, const unsigned char* __restrict__ code,
    const float* __restrict__ outk, float* __restrict__ out) {
  int blk = (T_ * B_ * C_ - 1) - blockIdx.x;  // reversed (t*B + b)*C + c
  int c = blk % C_;
  int tb = blk / C_;
  int b = tb % B_;
  int t = tb / B_;

  const float* ob = outk + ((b * T_ + t) * K_) * C_ + c;
  float o0 = ob[0 * C_], o1 = ob[1 * C_], o2 = ob[2 * C_];

  const float4* xp = (const float4*)(x + (size_t)blk * HW_);
  float4* op = (float4*)(out + (size_t)blk * HW_);
  const unsigned char* cp = code + (b * T_ + t) * HW0_;

  for (int i = threadIdx.x; i < HW_ / 4; i += 256) {
    float4 v = xp[i];
    int p = i * 4;
    int h = p / W_;
    int w = p - h * W_;
    const unsigned char* crow = cp + (h >> 1) * W0_ + (w >> 1);
    int ca = crow[0];
    int cb = crow[1];
    float addA = (ca & 1 ? o0 : 0.f) + (ca & 2 ? o1 : 0.f) + (ca & 4 ? o2 : 0.f);
    float addB = (cb & 1 ? o0 : 0.f) + (cb & 2 ? o1 : 0.f) + (cb & 4 ? o2 : 0.f);
    v.x += addA;
    v.y += addA;
    v.z += addB;
    v.w += addB;
    op[i] = v;
  }
}

extern "C" void kernel_launch(void* const* d_in, const int* in_sizes, int n_in,
                              void* d_out, int out_size, void* d_ws,
                              size_t ws_size, hipStream_t stream) {
  const float* x = (const float*)d_in[0];
  const int* masks = (const int*)d_in[1];
  const float* W_emb = (const float*)d_in[2];
  const float* W_gcn = (const float*)d_in[3];
  const float* b_gcn = (const float*)d_in[4];
  float* out = (float*)d_out;

  // workspace layout (all 256-aligned):
  //   code: B*T*H0*W0 bytes        = 150528
  //   feat: B*T*K*C floats         = 110592 bytes
  //   outk: B*T*K*C floats         = 110592 bytes
  //   Wf:   C*C floats             = 147456 bytes
  unsigned char* code = (unsigned char*)d_ws;
  float* feat = (float*)((char*)d_ws + 150528);
  float* outk = (float*)((char*)d_ws + 150528 + 110592);
  float* Wf = (float*)((char*)d_ws + 150528 + 110592 + 110592);

  prep_kernel<<<CODE_BLOCKS + C_, 256, 0, stream>>>(masks, code, W_emb, W_gcn,
                                                    Wf);
  pool_kernel<<<T_ * B_ * C_, 256, 0, stream>>>(x, code, feat);
  gcn_kernel<<<B_, 256, 0, stream>>>(feat, Wf, b_gcn, outk);
  out_kernel<<<T_ * B_ * C_, 256, 0, stream>>>(x, code, outk, out);
}

// Round 3
// 949.249 us; speedup vs baseline: 1.0295x; 1.0198x over previous
//
#include <hip/hip_runtime.h>

#define T_ 6
#define B_ 8
#define C_ 192
#define H_ 112
#define W_ 112
#define K_ 3
#define H0_ 56
#define W0_ 56
#define N_ (T_ * K_)      // 18
#define HW_ (H_ * W_)     // 12544
#define HW0_ (H0_ * W0_)  // 3136
#define CODE_BLOCKS 588   // B*T*HW0 / 256 = 150528/256 exactly

typedef float f32x4 __attribute__((ext_vector_type(4)));  // native vector:
// __builtin_nontemporal_* requires a clang vector type, not HIP_vector_type.

// ---------------------------------------------------------------------------
// Kernel A (fused prep):
//  blocks [0,588):   pack 3 binary masks into a 3-bit code per (b,t,h0,w0)
//  blocks [588,780): Wf[c][e] = sum_d W_emb[d][c] * W_gcn[d][e]
//                    (algebraic fusion: support = node @ (W_emb^T @ W_gcn))
// ---------------------------------------------------------------------------
__global__ __launch_bounds__(256) void prep_kernel(
    const int* __restrict__ masks, unsigned char* __restrict__ code,
    const float* __restrict__ W_emb, const float* __restrict__ W_gcn,
    float* __restrict__ Wf) {
  int blk = blockIdx.x;
  if (blk < CODE_BLOCKS) {
    int idx = blk * 256 + threadIdx.x;  // over B*T*H0*W0 = 150528 (exact)
    int p = idx % HW0_;
    int bt = idx / HW0_;  // b*T + t
    const int base = bt * K_ * HW0_;
    int c0 = masks[base + 0 * HW0_ + p];
    int c1 = masks[base + 1 * HW0_ + p];
    int c2 = masks[base + 2 * HW0_ + p];
    code[idx] = (unsigned char)((c0 & 1) | ((c1 & 1) << 1) | ((c2 & 1) << 2));
  } else {
    int c = blk - CODE_BLOCKS;  // 0..191
    int e = threadIdx.x;
    if (e < C_) {
      float s = 0.f;
      // W_emb[d*C+c] is wave-uniform (scalar path); W_gcn[d*C+e] coalesced.
#pragma unroll 4
      for (int d = 0; d < C_; ++d) s += W_emb[d * C_ + c] * W_gcn[d * C_ + e];
      Wf[c * C_ + e] = s;
    }
  }
}

// ---------------------------------------------------------------------------
// Kernel B: masked pooling. One block per (t,b,c) plane (x layout order).
// feat[b][t][k][c] = (1/HW) * sum_{h,w} x[t,b,c,h,w] * m[b,t,k,h,w]
// Regular (allocating) loads on purpose: the tail of x should stay in L3
// for out_kernel's reversed pass.
// ---------------------------------------------------------------------------
__global__ __launch_bounds__(256) void pool_kernel(
    const float* __restrict__ x, const unsigned char* __restrict__ code,
    float* __restrict__ feat) {
  int blk = blockIdx.x;  // (t*B + b)*C + c
  int c = blk % C_;
  int tb = blk / C_;  // t*B + b
  int b = tb % B_;
  int t = tb / B_;

  const float4* xp = (const float4*)(x + (size_t)blk * HW_);
  const unsigned char* cp = code + (b * T_ + t) * HW0_;

  float s0 = 0.f, s1 = 0.f, s2 = 0.f;
  // W_=112 divisible by 4 -> each float4 stays within one row.
  for (int i = threadIdx.x; i < HW_ / 4; i += 256) {
    float4 v = xp[i];
    int p = i * 4;
    int h = p / W_;
    int w = p - h * W_;
    const unsigned char* crow = cp + (h >> 1) * W0_ + (w >> 1);
    int ca = crow[0];  // covers pixels w, w+1
    int cb = crow[1];  // covers pixels w+2, w+3
    float pa = v.x + v.y;
    float pb = v.z + v.w;
    s0 += (ca & 1 ? pa : 0.f) + (cb & 1 ? pb : 0.f);
    s1 += (ca & 2 ? pa : 0.f) + (cb & 2 ? pb : 0.f);
    s2 += (ca & 4 ? pa : 0.f) + (cb & 4 ? pb : 0.f);
  }

  // wave (64-lane) reduce, then LDS across the 4 waves
  for (int off = 32; off > 0; off >>= 1) {
    s0 += __shfl_down(s0, off);
    s1 += __shfl_down(s1, off);
    s2 += __shfl_down(s2, off);
  }
  __shared__ float red[4][3];
  int lane = threadIdx.x & 63;
  int wid = threadIdx.x >> 6;
  if (lane == 0) {
    red[wid][0] = s0;
    red[wid][1] = s1;
    red[wid][2] = s2;
  }
  __syncthreads();
  if (threadIdx.x == 0) {
    const float inv_hw = 1.0f / (float)HW_;
    float f0 = (red[0][0] + red[1][0] + red[2][0] + red[3][0]) * inv_hw;
    float f1 = (red[0][1] + red[1][1] + red[2][1] + red[3][1]) * inv_hw;
    float f2 = (red[0][2] + red[1][2] + red[2][2] + red[3][2]) * inv_hw;
    float* fb = feat + ((b * T_ + t) * K_) * C_ + c;
    fb[0 * C_] = f0;
    fb[1 * C_] = f1;
    fb[2 * C_] = f2;
  }
}

// ---------------------------------------------------------------------------
// Kernel C: per-batch GCN.
//   node = feat (already /HW); adj = softmax(node node^T);
//   sup  = node @ Wf; outk = adj @ sup + b_gcn
// ---------------------------------------------------------------------------
__global__ __launch_bounds__(256) void gcn_kernel(
    const float* __restrict__ feat, const float* __restrict__ Wf,
    const float* __restrict__ b_gcn, float* __restrict__ outk) {
  int b = blockIdx.x;
  int tid = threadIdx.x;
  __shared__ float node[N_][C_ + 1];  // +1: odd stride breaks gram's
                                      // same-bank conflicts (192%32==0)
  __shared__ float sup[N_][C_];
  __shared__ float adj[N_][N_];

  for (int i = tid; i < N_ * C_; i += 256)
    node[i / C_][i % C_] = feat[b * N_ * C_ + i];
  __syncthreads();

  // gram
  for (int i = tid; i < N_ * N_; i += 256) {
    int n = i / N_, m = i % N_;
    float s = 0.f;
#pragma unroll 8
    for (int c = 0; c < C_; ++c) s += node[n][c] * node[m][c];
    adj[n][m] = s;
  }
  __syncthreads();

  // softmax rows (18 rows, one thread each; fully unrolled -> registers)
  if (tid < N_) {
    float mx = -1e30f;
#pragma unroll
    for (int m = 0; m < N_; ++m) mx = fmaxf(mx, adj[tid][m]);
    float tmp[N_];
    float sum = 0.f;
#pragma unroll
    for (int m = 0; m < N_; ++m) {
      tmp[m] = __expf(adj[tid][m] - mx);
      sum += tmp[m];
    }
    float inv = 1.0f / sum;
#pragma unroll
    for (int m = 0; m < N_; ++m) adj[tid][m] = tmp[m] * inv;
  }
  __syncthreads();

  // sup[n][e] = sum_c node[n][c] * Wf[c][e]   (Wf read coalesced, L2-hot)
  for (int i = tid; i < N_ * C_; i += 256) {
    int n = i / C_, e = i % C_;
    float s = 0.f;
#pragma unroll 4
    for (int c = 0; c < C_; ++c) s += node[n][c] * Wf[c * C_ + e];
    sup[n][e] = s;
  }
  __syncthreads();

  // outk[n][e] = sum_m adj[n][m] * sup[m][e] + b_gcn[e]
  for (int i = tid; i < N_ * C_; i += 256) {
    int n = i / C_, e = i % C_;
    float s = b_gcn[e];
#pragma unroll
    for (int m = 0; m < N_; ++m) s += adj[n][m] * sup[m][e];
    outk[b * N_ * C_ + i] = s;
  }
}

// ---------------------------------------------------------------------------
// Kernel D: out = x + sum_k outk[b,t,k,c] * m[b,t,k,h,w].
// Reversed plane order (consume pool's L3-resident tail first) and
// NON-TEMPORAL x-loads and out-stores: neither is ever re-read by us, and
// allocating the 462 MB write stream in L3 would evict the x-tail that the
// reversed reads are trying to hit.
// ---------------------------------------------------------------------------
__global__ __launch_bounds__(256) void out_kernel(
    const float* __restrict__ x, const unsigned char* __restrict__ code,
    const float* __restrict__ outk, float* __restrict__ out) {
  int blk = (T_ * B_ * C_ - 1) - blockIdx.x;  // reversed (t*B + b)*C + c
  int c = blk % C_;
  int tb = blk / C_;
  int b = tb % B_;
  int t = tb / B_;

  const float* ob = outk + ((b * T_ + t) * K_) * C_ + c;
  float o0 = ob[0 * C_], o1 = ob[1 * C_], o2 = ob[2 * C_];

  const f32x4* xp = (const f32x4*)(x + (size_t)blk * HW_);
  f32x4* op = (f32x4*)(out + (size_t)blk * HW_);
  const unsigned char* cp = code + (b * T_ + t) * HW0_;

  for (int i = threadIdx.x; i < HW_ / 4; i += 256) {
    f32x4 v = __builtin_nontemporal_load(&xp[i]);
    int p = i * 4;
    int h = p / W_;
    int w = p - h * W_;
    const unsigned char* crow = cp + (h >> 1) * W0_ + (w >> 1);
    int ca = crow[0];
    int cb = crow[1];
    float addA = (ca & 1 ? o0 : 0.f) + (ca & 2 ? o1 : 0.f) + (ca & 4 ? o2 : 0.f);
    float addB = (cb & 1 ? o0 : 0.f) + (cb & 2 ? o1 : 0.f) + (cb & 4 ? o2 : 0.f);
    v.x += addA;
    v.y += addA;
    v.z += addB;
    v.w += addB;
    __builtin_nontemporal_store(v, &op[i]);
  }
}

extern "C" void kernel_launch(void* const* d_in, const int* in_sizes, int n_in,
                              void* d_out, int out_size, void* d_ws,
                              size_t ws_size, hipStream_t stream) {
  const float* x = (const float*)d_in[0];
  const int* masks = (const int*)d_in[1];
  const float* W_emb = (const float*)d_in[2];
  const float* W_gcn = (const float*)d_in[3];
  const float* b_gcn = (const float*)d_in[4];
  float* out = (float*)d_out;

  // workspace layout (all 256-aligned):
  //   code: B*T*H0*W0 bytes        = 150528
  //   feat: B*T*K*C floats         = 110592 bytes
  //   outk: B*T*K*C floats         = 110592 bytes
  //   Wf:   C*C floats             = 147456 bytes
  unsigned char* code = (unsigned char*)d_ws;
  float* feat = (float*)((char*)d_ws + 150528);
  float* outk = (float*)((char*)d_ws + 150528 + 110592);
  float* Wf = (float*)((char*)d_ws + 150528 + 110592 + 110592);

  prep_kernel<<<CODE_BLOCKS + C_, 256, 0, stream>>>(masks, code, W_emb, W_gcn,
                                                    Wf);
  pool_kernel<<<T_ * B_ * C_, 256, 0, stream>>>(x, code, feat);
  gcn_kernel<<<B_, 256, 0, stream>>>(feat, Wf, b_gcn, outk);
  out_kernel<<<T_ * B_ * C_, 256, 0, stream>>>(x, code, outk, out);
}